// Round 8
// baseline (219.559 us; speedup 1.0000x reference)
//
#include <hip/hip_runtime.h>
#include <math.h>

#define CCH 256      // channels C
#define OCH 50       // output channels O
#define NPIX 16384   // H*W
#define BATCH 4
#define BO (BATCH*OCH)   // 200
#define NSPLIT2 256      // K-split (64-pixel chunks) for S GEMM
#define KC2 (NPIX/NSPLIT2)  // 64 pixels per ks chunk

typedef _Float16 f16x8 __attribute__((ext_vector_type(8)));
typedef float f32x4 __attribute__((ext_vector_type(4)));
typedef unsigned int uint;
typedef unsigned short ushort;

// split fp32 -> f16 hi + f16 lo (x ~= h + l, rel err ~2^-22)
__device__ __forceinline__ void cvt_split(const float4 v0, const float4 v1,
                                          f16x8& h, f16x8& l) {
    float v[8] = {v0.x, v0.y, v0.z, v0.w, v1.x, v1.y, v1.z, v1.w};
#pragma unroll
    for (int j = 0; j < 8; ++j) {
        _Float16 hj = (_Float16)v[j];
        h[j] = hj;
        l[j] = (_Float16)(v[j] - (float)hj);
    }
}

__device__ __forceinline__ uint packhl(float v) {
    _Float16 h = (_Float16)v;
    _Float16 l = (_Float16)(v - (float)h);
    union { _Float16 f; ushort u; } H, L;
    H.f = h; L.f = l;
    return (uint)H.u | ((uint)L.u << 16);
}

// 8 packed (h|l<<16) words -> f16x8 h-vec and l-vec (v_perm pairs)
__device__ __forceinline__ void unpack8(const uint* w, f16x8& h, f16x8& l) {
    union { uint u[4]; f16x8 v; } H, L;
#pragma unroll
    for (int k = 0; k < 4; ++k) {
        H.u[k] = __builtin_amdgcn_perm(w[2 * k + 1], w[2 * k], 0x05040100u);
        L.u[k] = __builtin_amdgcn_perm(w[2 * k + 1], w[2 * k], 0x07060302u);
    }
    h = H.v; l = L.v;
}

// ---------- K0: pack W_f [50,256] -> Wf16p [64,256] u32 (h|l<<16), zero-padded ----------
__global__ void k0_pack(const float* __restrict__ Wf, uint* __restrict__ Wf16p) {
    int i = blockIdx.x * 256 + threadIdx.x;   // 64*256
    if (i < 64 * CCH) {
        int o = i / CCH;
        float v = (o < OCH) ? Wf[i] : 0.f;
        Wf16p[i] = packhl(v);
    }
}

// ---------- K12: fused F-GEMM + S-partial GEMM over one 64-pixel chunk ----------
// Stage 1: F[o64, pix64] = Wf * x (LDS-staged x, c-minor swizzled). No F store.
// Handoff: per-wave F transpose via LDS (C/D lane=pix -> A-frag lane=o).
// Stage 2: Spart[o64, c256] = F * x^T over same 64 pixels (x re-read, L1/L2-hot).
__global__ __launch_bounds__(256, 4) void k12_mfma(const float* __restrict__ x,
                                                   const uint* __restrict__ Wf16p,
                                                   float* __restrict__ Spart) {
    int b  = blockIdx.y;
    int ks = blockIdx.x;        // 0..255
    int p0 = ks * KC2;          // 64-pixel chunk
    int t  = threadIdx.x;
    int w = t >> 6, lane = t & 63, r16 = lane & 15, kg = lane >> 4;
    __shared__ uint xl[2][32 * 64];
    __shared__ float Ft[4][16 * 68];   // per-wave F-transpose area

    int cidx = t & 15;          // staging c row 0..15 (+16 for second reg)
    int pixg = t >> 4;          // staging pixel group 0..15 (4 pixels each)
    const float* xb = x + ((size_t)b * CCH) * NPIX + p0;

    float4 r0 = *(const float4*)(xb + (size_t)cidx * NPIX + pixg * 4);
    float4 r1 = *(const float4*)(xb + (size_t)(16 + cidx) * NPIX + pixg * 4);

    f32x4 acc[4];
#pragma unroll
    for (int nt = 0; nt < 4; ++nt) acc[nt] = {0.f, 0.f, 0.f, 0.f};

    const uint* Arow = Wf16p + (w * 16 + r16) * CCH;

    // prologue: pack + write stage 0
    {
        float v0[4] = {r0.x, r0.y, r0.z, r0.w};
        float v1[4] = {r1.x, r1.y, r1.z, r1.w};
#pragma unroll
        for (int j = 0; j < 4; ++j) {
            int pix = pixg * 4 + j;
            int q = (pix & 7) << 2;
            xl[0][pix * 32 + (cidx ^ q)]        = packhl(v0[j]);
            xl[0][pix * 32 + ((16 + cidx) ^ q)] = packhl(v1[j]);
        }
    }
    __syncthreads();

#pragma unroll
    for (int s = 0; s < 8; ++s) {
        // issue next-stage global loads right AFTER the barrier
        if (s < 7) {
            r0 = *(const float4*)(xb + (size_t)((s + 1) * 32 + cidx) * NPIX + pixg * 4);
            r1 = *(const float4*)(xb + (size_t)((s + 1) * 32 + 16 + cidx) * NPIX + pixg * 4);
        }
        // A-frag: 8 packed words from Wf16p row (L2-hot)
        uint aw[8];
        *(uint4*)aw       = *(const uint4*)(Arow + s * 32 + kg * 8);
        *(uint4*)(aw + 4) = *(const uint4*)(Arow + s * 32 + kg * 8 + 4);
        f16x8 Ah, Al;
        unpack8(aw, Ah, Al);

        const uint* buf = xl[s & 1];
#pragma unroll
        for (int nt = 0; nt < 4; ++nt) {
            int pix = nt * 16 + r16;
            int q = (r16 & 7) << 2;
            uint bw[8];
            *(uint4*)bw       = *(const uint4*)&buf[pix * 32 + ((kg * 8) ^ q)];
            *(uint4*)(bw + 4) = *(const uint4*)&buf[pix * 32 + ((kg * 8 + 4) ^ q)];
            f16x8 Bh, Bl;
            unpack8(bw, Bh, Bl);
            acc[nt] = __builtin_amdgcn_mfma_f32_16x16x32_f16(Ah, Bh, acc[nt], 0, 0, 0);
            acc[nt] = __builtin_amdgcn_mfma_f32_16x16x32_f16(Ah, Bl, acc[nt], 0, 0, 0);
            acc[nt] = __builtin_amdgcn_mfma_f32_16x16x32_f16(Al, Bh, acc[nt], 0, 0, 0);
        }
        // pack + write next stage (consumes the prefetch), then barrier
        if (s < 7) {
            float v0[4] = {r0.x, r0.y, r0.z, r0.w};
            float v1[4] = {r1.x, r1.y, r1.z, r1.w};
            uint* nbuf = xl[(s + 1) & 1];
#pragma unroll
            for (int j = 0; j < 4; ++j) {
                int pix = pixg * 4 + j;
                int q = (pix & 7) << 2;
                nbuf[pix * 32 + (cidx ^ q)]        = packhl(v0[j]);
                nbuf[pix * 32 + ((16 + cidx) ^ q)] = packhl(v1[j]);
            }
            __syncthreads();
        }
    }

    // handoff: per-wave F transpose (C/D lane=pix -> A-frag lane=o)
    float* ft = Ft[w];
#pragma unroll
    for (int nt = 0; nt < 4; ++nt)
#pragma unroll
        for (int r = 0; r < 4; ++r)
            ft[(kg * 4 + r) * 68 + nt * 16 + r16] = acc[nt][r];
    __syncthreads();

    f16x8 Ah0, Al0, Ah1, Al1;
    {
        const float* fr = ft + r16 * 68;     // o = w*16 + r16, pix k = kk*32 + kg*8 + j
        cvt_split(*(const float4*)(fr + kg * 8), *(const float4*)(fr + kg * 8 + 4), Ah0, Al0);
        cvt_split(*(const float4*)(fr + 32 + kg * 8), *(const float4*)(fr + 32 + kg * 8 + 4), Ah1, Al1);
    }

    // stage 2: Spart rows = wave's 16 o, cols = 256 c (two passes of 8 c-tiles)
    const float* Bb = x + ((size_t)b * CCH) * NPIX + p0 + kg * 8;
#pragma unroll
    for (int half = 0; half < 2; ++half) {
        f32x4 sacc[8];
#pragma unroll
        for (int i = 0; i < 8; ++i) sacc[i] = {0.f, 0.f, 0.f, 0.f};
#pragma unroll
        for (int ct = 0; ct < 8; ++ct) {
            int c = (half * 8 + ct) * 16 + r16;
            const float* bp = Bb + (size_t)c * NPIX;
            f16x8 bh, bl;
            cvt_split(*(const float4*)bp, *(const float4*)(bp + 4), bh, bl);
            sacc[ct] = __builtin_amdgcn_mfma_f32_16x16x32_f16(Ah0, bh, sacc[ct], 0, 0, 0);
            sacc[ct] = __builtin_amdgcn_mfma_f32_16x16x32_f16(Ah0, bl, sacc[ct], 0, 0, 0);
            sacc[ct] = __builtin_amdgcn_mfma_f32_16x16x32_f16(Al0, bh, sacc[ct], 0, 0, 0);
            cvt_split(*(const float4*)(bp + 32), *(const float4*)(bp + 36), bh, bl);
            sacc[ct] = __builtin_amdgcn_mfma_f32_16x16x32_f16(Ah1, bh, sacc[ct], 0, 0, 0);
            sacc[ct] = __builtin_amdgcn_mfma_f32_16x16x32_f16(Ah1, bl, sacc[ct], 0, 0, 0);
            sacc[ct] = __builtin_amdgcn_mfma_f32_16x16x32_f16(Al1, bh, sacc[ct], 0, 0, 0);
        }
        // store: row = w*16 + kg*4 + r, col = half*128 + ct*16 + r16
        float* Sp = Spart + (((size_t)ks * BATCH + b) * 64 + w * 16 + kg * 4) * 256
                  + half * 128 + r16;
#pragma unroll
        for (int ct = 0; ct < 8; ++ct)
#pragma unroll
            for (int r = 0; r < 4; ++r)
                Sp[(size_t)r * 256 + ct * 16] = sacc[ct][r];
    }
}

// ---------- K2r: reduce partials (4-way split) + softmax over c ----------
__global__ __launch_bounds__(1024) void k2r_softmax(const float* __restrict__ Spart,
                                                    float* __restrict__ S) {
    int row = blockIdx.x;   // 0..199
    int b = row / OCH, o = row % OCH;
    int tid = threadIdx.x;
    int c = tid & 255, g = tid >> 8;           // g in 0..3
    __shared__ float part[4][CCH];
    __shared__ float red[8];
    float v = 0.f;
    const size_t ksStride = (size_t)BATCH * 64 * 256;
    const float* p = Spart + ((size_t)(g * (NSPLIT2 / 4)) * BATCH + b) * 64 * 256
                   + (size_t)o * 256 + c;
#pragma unroll 8
    for (int ks = 0; ks < NSPLIT2 / 4; ++ks)
        v += p[ks * ksStride];
    part[g][c] = v;
    __syncthreads();
    float vv = 0.f, e = 0.f, m;
    if (tid < 256) {
        vv = part[0][c] + part[1][c] + part[2][c] + part[3][c];
        m = vv;
#pragma unroll
        for (int off = 32; off > 0; off >>= 1) m = fmaxf(m, __shfl_xor(m, off, 64));
        if ((tid & 63) == 0) red[tid >> 6] = m;
    }
    __syncthreads();
    if (tid < 256) {
        m = fmaxf(fmaxf(red[0], red[1]), fmaxf(red[2], red[3]));
        e = expf(vv - m);
        float s = e;
#pragma unroll
        for (int off = 32; off > 0; off >>= 1) s += __shfl_xor(s, off, 64);
        if ((tid & 63) == 0) red[4 + (tid >> 6)] = s;
    }
    __syncthreads();
    if (tid < 256) {
        float tot = red[4] + red[5] + red[6] + red[7];
        S[(size_t)row * CCH + c] = e / tot;
    }
}

// ---------- K3: Mt[b*O+o, d] = sum_c Wbeta[d,c] * S[b*O+o, c] ----------
__global__ __launch_bounds__(256) void k3_M(const float* __restrict__ Wbeta,
                                            const float* __restrict__ S,
                                            float* __restrict__ Mt) {
    int row = blockIdx.x;   // b*O+o
    int d = threadIdx.x;
    const float* srow = S + (size_t)row * CCH;
    const float4* wb = (const float4*)(Wbeta + (size_t)d * CCH);
    float acc = 0.f;
#pragma unroll 4
    for (int cg = 0; cg < CCH / 4; ++cg) {
        float4 w = wb[cg];
        float4 s = *(const float4*)(srow + cg * 4);   // uniform -> s_load
        acc += w.x * s.x + w.y * s.y + w.z * s.z + w.w * s.w;
    }
    Mt[(size_t)row * CCH + d] = acc;
}

// ---------- K3b: G[b,d,c] = sum_o Mt[b,o,d] * Wf[o,c], packed (h|l) u32 ----------
__global__ __launch_bounds__(256) void k3b_G(const float* __restrict__ Mt,
                                             const float* __restrict__ Wf,
                                             uint* __restrict__ Gp) {
    int bd = blockIdx.x;        // b*256 + d
    int b = bd >> 8, d = bd & 255;
    int c = threadIdx.x;
    float acc = 0.f;
    const float* mp = Mt + ((size_t)b * OCH) * CCH + d;   // uniform per block
#pragma unroll 5
    for (int o = 0; o < OCH; ++o)
        acc = fmaf(mp[(size_t)o * CCH], Wf[o * CCH + c], acc);
    Gp[(size_t)bd * CCH + c] = packhl(acc);
}

// ---------- K4: out[b,d,n] = sum_c G[b,d,c] * x[b,c,n] + x[b,d,n]  (MFMA) ----------
// Block = (b, 64-pixel chunk). Wave w owns d-rows [64w, 64w+64) (4 m-tiles).
// LDS-staged x tile (same as k12 stage 1), A-frags from packed G (L2-hot).
__global__ __launch_bounds__(256, 3) void k4_mfma(const float* __restrict__ x,
                                                  const uint* __restrict__ Gp,
                                                  float* __restrict__ out) {
    int b  = blockIdx.y;
    int ks = blockIdx.x;
    int p0 = ks * KC2;
    int t  = threadIdx.x;
    int w = t >> 6, lane = t & 63, r16 = lane & 15, kg = lane >> 4;
    __shared__ uint xl[2][32 * 64];

    int cidx = t & 15;
    int pixg = t >> 4;
    const float* xb = x + ((size_t)b * CCH) * NPIX + p0;

    float4 r0 = *(const float4*)(xb + (size_t)cidx * NPIX + pixg * 4);
    float4 r1 = *(const float4*)(xb + (size_t)(16 + cidx) * NPIX + pixg * 4);

    f32x4 acc[4][4];
#pragma unroll
    for (int mt = 0; mt < 4; ++mt)
#pragma unroll
        for (int nt = 0; nt < 4; ++nt) acc[mt][nt] = {0.f, 0.f, 0.f, 0.f};

    const uint* Gb = Gp + ((size_t)b * 256 + w * 64 + r16) * CCH;   // + mt*16*CCH rows

    // prologue: pack + write stage 0
    {
        float v0[4] = {r0.x, r0.y, r0.z, r0.w};
        float v1[4] = {r1.x, r1.y, r1.z, r1.w};
#pragma unroll
        for (int j = 0; j < 4; ++j) {
            int pix = pixg * 4 + j;
            int q = (pix & 7) << 2;
            xl[0][pix * 32 + (cidx ^ q)]        = packhl(v0[j]);
            xl[0][pix * 32 + ((16 + cidx) ^ q)] = packhl(v1[j]);
        }
    }
    __syncthreads();

#pragma unroll
    for (int s = 0; s < 8; ++s) {
        if (s < 7) {
            r0 = *(const float4*)(xb + (size_t)((s + 1) * 32 + cidx) * NPIX + pixg * 4);
            r1 = *(const float4*)(xb + (size_t)((s + 1) * 32 + 16 + cidx) * NPIX + pixg * 4);
        }
        // B-frags for the 4 pixel-tiles from LDS
        f16x8 Bh[4], Bl[4];
        const uint* buf = xl[s & 1];
        int q = (r16 & 7) << 2;
#pragma unroll
        for (int nt = 0; nt < 4; ++nt) {
            int pix = nt * 16 + r16;
            uint bw[8];
            *(uint4*)bw       = *(const uint4*)&buf[pix * 32 + ((kg * 8) ^ q)];
            *(uint4*)(bw + 4) = *(const uint4*)&buf[pix * 32 + ((kg * 8 + 4) ^ q)];
            unpack8(bw, Bh[nt], Bl[nt]);
        }
        // A per m-tile from packed G, 12 MFMA each
#pragma unroll
        for (int mt = 0; mt < 4; ++mt) {
            uint aw[8];
            const uint* ap = Gb + (size_t)(mt * 16) * CCH + s * 32 + kg * 8;
            *(uint4*)aw       = *(const uint4*)ap;
            *(uint4*)(aw + 4) = *(const uint4*)(ap + 4);
            f16x8 Ah, Al;
            unpack8(aw, Ah, Al);
#pragma unroll
            for (int nt = 0; nt < 4; ++nt) {
                acc[mt][nt] = __builtin_amdgcn_mfma_f32_16x16x32_f16(Ah, Bh[nt], acc[mt][nt], 0, 0, 0);
                acc[mt][nt] = __builtin_amdgcn_mfma_f32_16x16x32_f16(Ah, Bl[nt], acc[mt][nt], 0, 0, 0);
                acc[mt][nt] = __builtin_amdgcn_mfma_f32_16x16x32_f16(Al, Bh[nt], acc[mt][nt], 0, 0, 0);
            }
        }
        if (s < 7) {
            float v0[4] = {r0.x, r0.y, r0.z, r0.w};
            float v1[4] = {r1.x, r1.y, r1.z, r1.w};
            uint* nbuf = xl[(s + 1) & 1];
#pragma unroll
            for (int j = 0; j < 4; ++j) {
                int pix = pixg * 4 + j;
                int qq = (pix & 7) << 2;
                nbuf[pix * 32 + (cidx ^ qq)]        = packhl(v0[j]);
                nbuf[pix * 32 + ((16 + cidx) ^ qq)] = packhl(v1[j]);
            }
            __syncthreads();
        }
    }

    // epilogue: residual (fp32 x, L1/L2-hot) + nontemporal store
    // row d = w*64 + mt*16 + kg*4 + r, col pix = p0 + nt*16 + r16
    const float* xr = x + ((size_t)b * CCH + w * 64 + kg * 4) * NPIX + p0 + r16;
    float*       op = out + ((size_t)b * CCH + w * 64 + kg * 4) * NPIX + p0 + r16;
#pragma unroll
    for (int mt = 0; mt < 4; ++mt)
#pragma unroll
        for (int nt = 0; nt < 4; ++nt)
#pragma unroll
            for (int r = 0; r < 4; ++r) {
                size_t o2 = (size_t)(mt * 16 + r) * NPIX + nt * 16;
                __builtin_nontemporal_store(acc[mt][nt][r] + xr[o2], &op[o2]);
            }
}

extern "C" void kernel_launch(void* const* d_in, const int* in_sizes, int n_in,
                              void* d_out, int out_size, void* d_ws, size_t ws_size,
                              hipStream_t stream) {
    const float* x     = (const float*)d_in[0];   // [4,256,128,128]
    const float* Wf    = (const float*)d_in[1];   // [50,256]
    const float* Wbeta = (const float*)d_in[2];   // [256,256]
    float* out = (float*)d_out;

    // ws layout: Wf16p [64*256 u32] | S [BO*C f32] | Mt [BO*C f32] | Gp [B*256*256 u32]
    uint*  Wf16p = (uint*)d_ws;
    float* S     = (float*)(Wf16p + 64 * CCH);
    float* Mt    = S + (size_t)BO * CCH;
    uint*  Gp    = (uint*)(Mt + (size_t)BO * CCH);
    // S-partials live in d_out (free until K4): 256*4*64*256 = 16.78M floats == out_size
    float* Spart = out;

    k0_pack<<<dim3((64 * CCH + 255) / 256), dim3(256), 0, stream>>>(Wf, Wf16p);
    k12_mfma<<<dim3(NSPLIT2, BATCH), dim3(256), 0, stream>>>(x, Wf16p, Spart);
    k2r_softmax<<<dim3(BO), dim3(1024), 0, stream>>>(Spart, S);
    k3_M<<<dim3(BO), dim3(256), 0, stream>>>(Wbeta, S, Mt);
    k3b_G<<<dim3(BATCH * 256), dim3(256), 0, stream>>>(Mt, Wf, Gp);
    k4_mfma<<<dim3(NSPLIT2, BATCH), dim3(256), 0, stream>>>(x, Gp, out);
}

// Round 9
// 214.292 us; speedup vs baseline: 1.0246x; 1.0246x over previous
//
#include <hip/hip_runtime.h>
#include <math.h>

#define CCH 256      // channels C
#define OCH 50       // output channels O
#define NPIX 16384   // H*W
#define BATCH 4
#define BO (BATCH*OCH)   // 200
#define NSPLIT2 256      // K-split (64-pixel chunks) for S GEMM
#define KC2 (NPIX/NSPLIT2)  // 64 pixels per ks chunk

typedef _Float16 f16x8 __attribute__((ext_vector_type(8)));
typedef float f32x4 __attribute__((ext_vector_type(4)));
typedef unsigned int uint;
typedef unsigned short ushort;

// split fp32 -> f16 hi + f16 lo (x ~= h + l, rel err ~2^-22)
__device__ __forceinline__ void cvt_split(const float4 v0, const float4 v1,
                                          f16x8& h, f16x8& l) {
    float v[8] = {v0.x, v0.y, v0.z, v0.w, v1.x, v1.y, v1.z, v1.w};
#pragma unroll
    for (int j = 0; j < 8; ++j) {
        _Float16 hj = (_Float16)v[j];
        h[j] = hj;
        l[j] = (_Float16)(v[j] - (float)hj);
    }
}

__device__ __forceinline__ uint packhl(float v) {
    _Float16 h = (_Float16)v;
    _Float16 l = (_Float16)(v - (float)h);
    union { _Float16 f; ushort u; } H, L;
    H.f = h; L.f = l;
    return (uint)H.u | ((uint)L.u << 16);
}

// 8 packed (h|l<<16) words -> f16x8 h-vec and l-vec (v_perm pairs)
__device__ __forceinline__ void unpack8(const uint* w, f16x8& h, f16x8& l) {
    union { uint u[4]; f16x8 v; } H, L;
#pragma unroll
    for (int k = 0; k < 4; ++k) {
        H.u[k] = __builtin_amdgcn_perm(w[2 * k + 1], w[2 * k], 0x05040100u);
        L.u[k] = __builtin_amdgcn_perm(w[2 * k + 1], w[2 * k], 0x07060302u);
    }
    h = H.v; l = L.v;
}

// ---------- K0: pack W_f [50,256] -> Wf16p [64,256] u32 (h|l<<16), zero-padded ----------
__global__ void k0_pack(const float* __restrict__ Wf, uint* __restrict__ Wf16p) {
    int i = blockIdx.x * 256 + threadIdx.x;   // 64*256
    if (i < 64 * CCH) {
        int o = i / CCH;
        float v = (o < OCH) ? Wf[i] : 0.f;
        Wf16p[i] = packhl(v);
    }
}

// ---------- K12: fused F-GEMM + S-partial GEMM over one 64-pixel chunk ----------
__global__ __launch_bounds__(256, 4) void k12_mfma(const float* __restrict__ x,
                                                   const uint* __restrict__ Wf16p,
                                                   float* __restrict__ Spart) {
    int b  = blockIdx.y;
    int ks = blockIdx.x;        // 0..255
    int p0 = ks * KC2;          // 64-pixel chunk
    int t  = threadIdx.x;
    int w = t >> 6, lane = t & 63, r16 = lane & 15, kg = lane >> 4;
    __shared__ uint xl[2][32 * 64];
    __shared__ float Ft[4][16 * 68];   // per-wave F-transpose area

    int cidx = t & 15;          // staging c row 0..15 (+16 for second reg)
    int pixg = t >> 4;          // staging pixel group 0..15 (4 pixels each)
    const float* xb = x + ((size_t)b * CCH) * NPIX + p0;

    float4 r0 = *(const float4*)(xb + (size_t)cidx * NPIX + pixg * 4);
    float4 r1 = *(const float4*)(xb + (size_t)(16 + cidx) * NPIX + pixg * 4);

    f32x4 acc[4];
#pragma unroll
    for (int nt = 0; nt < 4; ++nt) acc[nt] = {0.f, 0.f, 0.f, 0.f};

    const uint* Arow = Wf16p + (w * 16 + r16) * CCH;

    // prologue: pack + write stage 0
    {
        float v0[4] = {r0.x, r0.y, r0.z, r0.w};
        float v1[4] = {r1.x, r1.y, r1.z, r1.w};
#pragma unroll
        for (int j = 0; j < 4; ++j) {
            int pix = pixg * 4 + j;
            int q = (pix & 7) << 2;
            xl[0][pix * 32 + (cidx ^ q)]        = packhl(v0[j]);
            xl[0][pix * 32 + ((16 + cidx) ^ q)] = packhl(v1[j]);
        }
    }
    __syncthreads();

#pragma unroll
    for (int s = 0; s < 8; ++s) {
        // issue next-stage global loads right AFTER the barrier
        if (s < 7) {
            r0 = *(const float4*)(xb + (size_t)((s + 1) * 32 + cidx) * NPIX + pixg * 4);
            r1 = *(const float4*)(xb + (size_t)((s + 1) * 32 + 16 + cidx) * NPIX + pixg * 4);
        }
        // A-frag: 8 packed words from Wf16p row (L2-hot)
        uint aw[8];
        *(uint4*)aw       = *(const uint4*)(Arow + s * 32 + kg * 8);
        *(uint4*)(aw + 4) = *(const uint4*)(Arow + s * 32 + kg * 8 + 4);
        f16x8 Ah, Al;
        unpack8(aw, Ah, Al);

        const uint* buf = xl[s & 1];
#pragma unroll
        for (int nt = 0; nt < 4; ++nt) {
            int pix = nt * 16 + r16;
            int q = (r16 & 7) << 2;
            uint bw[8];
            *(uint4*)bw       = *(const uint4*)&buf[pix * 32 + ((kg * 8) ^ q)];
            *(uint4*)(bw + 4) = *(const uint4*)&buf[pix * 32 + ((kg * 8 + 4) ^ q)];
            f16x8 Bh, Bl;
            unpack8(bw, Bh, Bl);
            acc[nt] = __builtin_amdgcn_mfma_f32_16x16x32_f16(Ah, Bh, acc[nt], 0, 0, 0);
            acc[nt] = __builtin_amdgcn_mfma_f32_16x16x32_f16(Ah, Bl, acc[nt], 0, 0, 0);
            acc[nt] = __builtin_amdgcn_mfma_f32_16x16x32_f16(Al, Bh, acc[nt], 0, 0, 0);
        }
        // pack + write next stage (consumes the prefetch), then barrier
        if (s < 7) {
            float v0[4] = {r0.x, r0.y, r0.z, r0.w};
            float v1[4] = {r1.x, r1.y, r1.z, r1.w};
            uint* nbuf = xl[(s + 1) & 1];
#pragma unroll
            for (int j = 0; j < 4; ++j) {
                int pix = pixg * 4 + j;
                int q = (pix & 7) << 2;
                nbuf[pix * 32 + (cidx ^ q)]        = packhl(v0[j]);
                nbuf[pix * 32 + ((16 + cidx) ^ q)] = packhl(v1[j]);
            }
            __syncthreads();
        }
    }

    // handoff: per-wave F transpose (C/D lane=pix -> A-frag lane=o)
    float* ft = Ft[w];
#pragma unroll
    for (int nt = 0; nt < 4; ++nt)
#pragma unroll
        for (int r = 0; r < 4; ++r)
            ft[(kg * 4 + r) * 68 + nt * 16 + r16] = acc[nt][r];
    __syncthreads();

    f16x8 Ah0, Al0, Ah1, Al1;
    {
        const float* fr = ft + r16 * 68;     // o = w*16 + r16, pix k = kk*32 + kg*8 + j
        cvt_split(*(const float4*)(fr + kg * 8), *(const float4*)(fr + kg * 8 + 4), Ah0, Al0);
        cvt_split(*(const float4*)(fr + 32 + kg * 8), *(const float4*)(fr + 32 + kg * 8 + 4), Ah1, Al1);
    }

    // stage 2: Spart rows = wave's 16 o, cols = 256 c (two passes of 8 c-tiles)
    const float* Bb = x + ((size_t)b * CCH) * NPIX + p0 + kg * 8;
#pragma unroll
    for (int half = 0; half < 2; ++half) {
        f32x4 sacc[8];
#pragma unroll
        for (int i = 0; i < 8; ++i) sacc[i] = {0.f, 0.f, 0.f, 0.f};
#pragma unroll
        for (int ct = 0; ct < 8; ++ct) {
            int c = (half * 8 + ct) * 16 + r16;
            const float* bp = Bb + (size_t)c * NPIX;
            f16x8 bh, bl;
            cvt_split(*(const float4*)bp, *(const float4*)(bp + 4), bh, bl);
            sacc[ct] = __builtin_amdgcn_mfma_f32_16x16x32_f16(Ah0, bh, sacc[ct], 0, 0, 0);
            sacc[ct] = __builtin_amdgcn_mfma_f32_16x16x32_f16(Ah0, bl, sacc[ct], 0, 0, 0);
            sacc[ct] = __builtin_amdgcn_mfma_f32_16x16x32_f16(Al0, bh, sacc[ct], 0, 0, 0);
            cvt_split(*(const float4*)(bp + 32), *(const float4*)(bp + 36), bh, bl);
            sacc[ct] = __builtin_amdgcn_mfma_f32_16x16x32_f16(Ah1, bh, sacc[ct], 0, 0, 0);
            sacc[ct] = __builtin_amdgcn_mfma_f32_16x16x32_f16(Ah1, bl, sacc[ct], 0, 0, 0);
            sacc[ct] = __builtin_amdgcn_mfma_f32_16x16x32_f16(Al1, bh, sacc[ct], 0, 0, 0);
        }
        // store: row = w*16 + kg*4 + r, col = half*128 + ct*16 + r16
        float* Sp = Spart + (((size_t)ks * BATCH + b) * 64 + w * 16 + kg * 4) * 256
                  + half * 128 + r16;
#pragma unroll
        for (int ct = 0; ct < 8; ++ct)
#pragma unroll
            for (int r = 0; r < 4; ++r)
                Sp[(size_t)r * 256 + ct * 16] = sacc[ct][r];
    }
}

// ---------- K2r: reduce partials (4-way split) + softmax over c ----------
__global__ __launch_bounds__(1024) void k2r_softmax(const float* __restrict__ Spart,
                                                    float* __restrict__ S) {
    int row = blockIdx.x;   // 0..199
    int b = row / OCH, o = row % OCH;
    int tid = threadIdx.x;
    int c = tid & 255, g = tid >> 8;           // g in 0..3
    __shared__ float part[4][CCH];
    __shared__ float red[8];
    float v = 0.f;
    const size_t ksStride = (size_t)BATCH * 64 * 256;
    const float* p = Spart + ((size_t)(g * (NSPLIT2 / 4)) * BATCH + b) * 64 * 256
                   + (size_t)o * 256 + c;
#pragma unroll 8
    for (int ks = 0; ks < NSPLIT2 / 4; ++ks)
        v += p[ks * ksStride];
    part[g][c] = v;
    __syncthreads();
    float vv = 0.f, e = 0.f, m;
    if (tid < 256) {
        vv = part[0][c] + part[1][c] + part[2][c] + part[3][c];
        m = vv;
#pragma unroll
        for (int off = 32; off > 0; off >>= 1) m = fmaxf(m, __shfl_xor(m, off, 64));
        if ((tid & 63) == 0) red[tid >> 6] = m;
    }
    __syncthreads();
    if (tid < 256) {
        m = fmaxf(fmaxf(red[0], red[1]), fmaxf(red[2], red[3]));
        e = expf(vv - m);
        float s = e;
#pragma unroll
        for (int off = 32; off > 0; off >>= 1) s += __shfl_xor(s, off, 64);
        if ((tid & 63) == 0) red[4 + (tid >> 6)] = s;
    }
    __syncthreads();
    if (tid < 256) {
        float tot = red[4] + red[5] + red[6] + red[7];
        S[(size_t)row * CCH + c] = e / tot;
    }
}

// ---------- K3: Mt[b*O+o, d] = sum_c Wbeta[d,c] * S[b*O+o, c] ----------
__global__ __launch_bounds__(256) void k3_M(const float* __restrict__ Wbeta,
                                            const float* __restrict__ S,
                                            float* __restrict__ Mt) {
    int row = blockIdx.x;   // b*O+o
    int d = threadIdx.x;
    const float* srow = S + (size_t)row * CCH;
    const float4* wb = (const float4*)(Wbeta + (size_t)d * CCH);
    float acc = 0.f;
#pragma unroll 4
    for (int cg = 0; cg < CCH / 4; ++cg) {
        float4 w = wb[cg];
        float4 s = *(const float4*)(srow + cg * 4);   // uniform -> s_load
        acc += w.x * s.x + w.y * s.y + w.z * s.z + w.w * s.w;
    }
    Mt[(size_t)row * CCH + d] = acc;
}

// ---------- K3b: G[b,d,c] = sum_o Mt[b,o,d] * Wf[o,c], packed (h|l) u32 ----------
__global__ __launch_bounds__(256) void k3b_G(const float* __restrict__ Mt,
                                             const float* __restrict__ Wf,
                                             uint* __restrict__ Gp) {
    int bd = blockIdx.x;        // b*256 + d
    int b = bd >> 8, d = bd & 255;
    int c = threadIdx.x;
    float acc = 0.f;
    const float* mp = Mt + ((size_t)b * OCH) * CCH + d;   // uniform per block
#pragma unroll 5
    for (int o = 0; o < OCH; ++o)
        acc = fmaf(mp[(size_t)o * CCH], Wf[o * CCH + c], acc);
    Gp[(size_t)bd * CCH + c] = packhl(acc);
}

// ---------- K4: out[b,d,n] = sum_c G[b,d,c] * x[b,c,n] + x[b,d,n]  (MFMA) ----------
// Fully pipelined: A(s+1) issued BEFORE x(s+1) prefetch, so the MFMA phase has
// zero vmcnt waits and end-of-stage x-wait drains A too (vmcnt ordering).
__global__ __launch_bounds__(256, 3) void k4_mfma(const float* __restrict__ x,
                                                  const uint* __restrict__ Gp,
                                                  float* __restrict__ out) {
    int b  = blockIdx.y;
    int ks = blockIdx.x;
    int p0 = ks * KC2;
    int t  = threadIdx.x;
    int w = t >> 6, lane = t & 63, r16 = lane & 15, kg = lane >> 4;
    __shared__ uint xl[2][32 * 64];

    int cidx = t & 15;
    int pixg = t >> 4;
    const float* xb = x + ((size_t)b * CCH) * NPIX + p0;
    const uint* Gb = Gp + ((size_t)b * 256 + w * 64 + r16) * CCH;

    // prologue: A(0) into registers
    uint aA[4][8];
#pragma unroll
    for (int mt = 0; mt < 4; ++mt) {
        const uint* ap = Gb + (size_t)(mt * 16) * CCH + kg * 8;
        *(uint4*)aA[mt]       = *(const uint4*)ap;
        *(uint4*)(aA[mt] + 4) = *(const uint4*)(ap + 4);
    }

    float4 r0 = *(const float4*)(xb + (size_t)cidx * NPIX + pixg * 4);
    float4 r1 = *(const float4*)(xb + (size_t)(16 + cidx) * NPIX + pixg * 4);

    f32x4 acc[4][4];
#pragma unroll
    for (int mt = 0; mt < 4; ++mt)
#pragma unroll
        for (int nt = 0; nt < 4; ++nt) acc[mt][nt] = {0.f, 0.f, 0.f, 0.f};

    // prologue: pack + write stage 0
    {
        float v0[4] = {r0.x, r0.y, r0.z, r0.w};
        float v1[4] = {r1.x, r1.y, r1.z, r1.w};
#pragma unroll
        for (int j = 0; j < 4; ++j) {
            int pix = pixg * 4 + j;
            int q = (pix & 7) << 2;
            xl[0][pix * 32 + (cidx ^ q)]        = packhl(v0[j]);
            xl[0][pix * 32 + ((16 + cidx) ^ q)] = packhl(v1[j]);
        }
    }
    __syncthreads();

    uint pA[4][8];
#pragma unroll
    for (int s = 0; s < 8; ++s) {
        // issue A(s+1) FIRST, then x(s+1): MFMA phase then needs no vmcnt wait,
        // and the LDS-write wait on r0/r1 (newest) drains pA as a side effect.
        if (s < 7) {
#pragma unroll
            for (int mt = 0; mt < 4; ++mt) {
                const uint* ap = Gb + (size_t)(mt * 16) * CCH + (s + 1) * 32 + kg * 8;
                *(uint4*)pA[mt]       = *(const uint4*)ap;
                *(uint4*)(pA[mt] + 4) = *(const uint4*)(ap + 4);
            }
            r0 = *(const float4*)(xb + (size_t)((s + 1) * 32 + cidx) * NPIX + pixg * 4);
            r1 = *(const float4*)(xb + (size_t)((s + 1) * 32 + 16 + cidx) * NPIX + pixg * 4);
        }
        // B-frags for the 4 pixel-tiles from LDS
        f16x8 Bh[4], Bl[4];
        const uint* buf = xl[s & 1];
        int q = (r16 & 7) << 2;
#pragma unroll
        for (int nt = 0; nt < 4; ++nt) {
            int pix = nt * 16 + r16;
            uint bw[8];
            *(uint4*)bw       = *(const uint4*)&buf[pix * 32 + ((kg * 8) ^ q)];
            *(uint4*)(bw + 4) = *(const uint4*)&buf[pix * 32 + ((kg * 8 + 4) ^ q)];
            unpack8(bw, Bh[nt], Bl[nt]);
        }
        // MFMA from registers only
#pragma unroll
        for (int mt = 0; mt < 4; ++mt) {
            f16x8 Ah, Al;
            unpack8(aA[mt], Ah, Al);
#pragma unroll
            for (int nt = 0; nt < 4; ++nt) {
                acc[mt][nt] = __builtin_amdgcn_mfma_f32_16x16x32_f16(Ah, Bh[nt], acc[mt][nt], 0, 0, 0);
                acc[mt][nt] = __builtin_amdgcn_mfma_f32_16x16x32_f16(Ah, Bl[nt], acc[mt][nt], 0, 0, 0);
                acc[mt][nt] = __builtin_amdgcn_mfma_f32_16x16x32_f16(Al, Bh[nt], acc[mt][nt], 0, 0, 0);
            }
        }
        if (s < 7) {
            float v0[4] = {r0.x, r0.y, r0.z, r0.w};
            float v1[4] = {r1.x, r1.y, r1.z, r1.w};
            uint* nbuf = xl[(s + 1) & 1];
#pragma unroll
            for (int j = 0; j < 4; ++j) {
                int pix = pixg * 4 + j;
                int qq = (pix & 7) << 2;
                nbuf[pix * 32 + (cidx ^ qq)]        = packhl(v0[j]);
                nbuf[pix * 32 + ((16 + cidx) ^ qq)] = packhl(v1[j]);
            }
            __syncthreads();
#pragma unroll
            for (int mt = 0; mt < 4; ++mt)
#pragma unroll
                for (int j = 0; j < 8; ++j) aA[mt][j] = pA[mt][j];
        }
    }

    // epilogue: residual (fp32 x, L1/L2-hot) + nontemporal store
    const float* xr = x + ((size_t)b * CCH + w * 64 + kg * 4) * NPIX + p0 + r16;
    float*       op = out + ((size_t)b * CCH + w * 64 + kg * 4) * NPIX + p0 + r16;
#pragma unroll
    for (int mt = 0; mt < 4; ++mt)
#pragma unroll
        for (int nt = 0; nt < 4; ++nt)
#pragma unroll
            for (int r = 0; r < 4; ++r) {
                size_t o2 = (size_t)(mt * 16 + r) * NPIX + nt * 16;
                __builtin_nontemporal_store(acc[mt][nt][r] + xr[o2], &op[o2]);
            }
}

extern "C" void kernel_launch(void* const* d_in, const int* in_sizes, int n_in,
                              void* d_out, int out_size, void* d_ws, size_t ws_size,
                              hipStream_t stream) {
    const float* x     = (const float*)d_in[0];   // [4,256,128,128]
    const float* Wf    = (const float*)d_in[1];   // [50,256]
    const float* Wbeta = (const float*)d_in[2];   // [256,256]
    float* out = (float*)d_out;

    // ws layout: Wf16p [64*256 u32] | S [BO*C f32] | Mt [BO*C f32] | Gp [B*256*256 u32]
    uint*  Wf16p = (uint*)d_ws;
    float* S     = (float*)(Wf16p + 64 * CCH);
    float* Mt    = S + (size_t)BO * CCH;
    uint*  Gp    = (uint*)(Mt + (size_t)BO * CCH);
    // S-partials live in d_out (free until K4): 256*4*64*256 = 16.78M floats == out_size
    float* Spart = out;

    k0_pack<<<dim3((64 * CCH + 255) / 256), dim3(256), 0, stream>>>(Wf, Wf16p);
    k12_mfma<<<dim3(NSPLIT2, BATCH), dim3(256), 0, stream>>>(x, Wf16p, Spart);
    k2r_softmax<<<dim3(BO), dim3(1024), 0, stream>>>(Spart, S);
    k3_M<<<dim3(BO), dim3(256), 0, stream>>>(Wbeta, S, Mt);
    k3b_G<<<dim3(BATCH * 256), dim3(256), 0, stream>>>(Mt, Wf, Gp);
    k4_mfma<<<dim3(NSPLIT2, BATCH), dim3(256), 0, stream>>>(x, Gp, out);
}